// Round 1
// 664.084 us; speedup vs baseline: 1.2420x; 1.2420x over previous
//
#include <hip/hip_runtime.h>
#include <hip/hip_fp16.h>

// SelfWarp on MI355X, round 3.
//  K1 vf_kernel  : fused value+flow. u staged to LDS ONCE per tile (was twice
//                  across two kernels). MFMA operand order swapped vs round 2:
//                  D[m=channel][n=pixel], so each lane holds 4 CONSECUTIVE
//                  output channels (q*4+r) of one pixel -> direct packed
//                  stores from accumulators, zero output LDS staging.
//                  Weight fragments are tile-invariant -> live in VGPRs
//                  (wave w owns channels [w*32,w*32+32) / flow [w*16,+16));
//                  no weight LDS. LDS = 16 KB, 4 barriers/tile (was 10).
//  K2 warp_kernel: periodic bilinear gather. value now stored channel-
//                  interleaved (b, head, pix, ci): one tap = one 8 B load
//                  (4 loads/thread instead of 16 x 2 B). Bijective XCD
//                  swizzle keeps consecutive rows of a head on one XCD's L2.
// ws: [0,134217728) value fp16 interleaved (b*32+head, pix, ci);
//     [+134217728,+67108864) flow packed u32 (lo16=x fp16, hi16=y fp16).

typedef unsigned short u16;
typedef unsigned int   u32;
using short8   = __attribute__((ext_vector_type(8))) short;   // 8 fp16
using f32x4    = __attribute__((ext_vector_type(4))) float;   // MFMA C/D
using ushort4v = __attribute__((ext_vector_type(4))) unsigned short;

#define HW     65536
#define NTILES 8192     // 524288 pixels / 64 per tile

__device__ __forceinline__ u16 f2h(float f) {
  return __half_as_ushort(__float2half(f));   // RNE
}
__device__ __forceinline__ float h2f(u16 h) {
  return __half2float(__ushort_as_half(h));
}

// A/B fragment for mfma_16x16x32_f16 from fp32 row: lane (q,m15) holds
// row (blk*16+m15), k = kc*32 + q*8 .. +8.
__device__ __forceinline__ short8 frag_from_f32(const float* __restrict__ src) {
  float4 a = *(const float4*)src;
  float4 b = *(const float4*)(src + 4);
  short8 r;
  r[0] = (short)f2h(a.x); r[1] = (short)f2h(a.y);
  r[2] = (short)f2h(a.z); r[3] = (short)f2h(a.w);
  r[4] = (short)f2h(b.x); r[5] = (short)f2h(b.y);
  r[6] = (short)f2h(b.z); r[7] = (short)f2h(b.w);
  return r;
}

// ---------------------------------------------------------------------------
// t_lds layout: [px 64][ch 128] fp16, row stride 256 B, 16 B chunk c of row p
// stored at chunk slot c ^ (p & 15). Used for the u tile, then reused for hmid.
__global__ __launch_bounds__(256) void vf_kernel(
    const float* __restrict__ u,  const float* __restrict__ w1,
    const float* __restrict__ b1, const float* __restrict__ w2,
    const float* __restrict__ b2, const float* __restrict__ wv,
    const float* __restrict__ bv, u16* __restrict__ vout,
    u32* __restrict__ fout)
{
  __shared__ u16 t_lds[64 * 128];   // 16 KB

  const int tid  = threadIdx.x;
  const int lane = tid & 63;
  const int w    = tid >> 6;        // wave id: owns ch [w*32,+32), fc [w*16,+16)
  const int m15  = lane & 15;
  const int q    = lane >> 4;

  // -- persistent weight fragments (tile-invariant, 80 VGPRs) --
  short8 w1f[2][4], wvf[2][4], w2f[4];
#pragma unroll
  for (int nt = 0; nt < 2; ++nt)
#pragma unroll
    for (int kc = 0; kc < 4; ++kc) {
      const int row = w * 32 + nt * 16 + m15;
      w1f[nt][kc] = frag_from_f32(w1 + row * 128 + kc * 32 + q * 8);
      wvf[nt][kc] = frag_from_f32(wv + row * 128 + kc * 32 + q * 8);
    }
#pragma unroll
  for (int kc = 0; kc < 4; ++kc)
    w2f[kc] = frag_from_f32(w2 + (w * 16 + m15) * 128 + kc * 32 + q * 8);

  // -- per-lane bias vectors: lane's 4 consecutive channels (q*4 + 0..3) --
  f32x4 vbias[2], hbias[2], fbias;
#pragma unroll
  for (int nt = 0; nt < 2; ++nt) {
    vbias[nt] = *(const f32x4*)(bv + w * 32 + nt * 16 + q * 4);
    hbias[nt] = *(const f32x4*)(b1 + w * 32 + nt * 16 + q * 4);
  }
  fbias = *(const f32x4*)(b2 + w * 16 + q * 4);

  for (int tile = blockIdx.x; tile < NTILES; tile += (int)gridDim.x) {
    const int gbase = tile << 6;
    const int b     = gbase >> 16;        // tiles never cross batch
    const int img   = gbase & 65535;
    const float* ub = u + ((size_t)b << 23) + img;

    {  // stage u tile: fp32 -> fp16, one uint4 (8 ch) per pass per thread
      const int p  = tid & 63;
      const int cb = (tid >> 6) << 3;
#pragma unroll
      for (int pass = 0; pass < 4; ++pass) {
        int c0 = cb + pass * 32;
        float v0 = ub[(size_t)(c0 + 0) * HW + p];
        float v1 = ub[(size_t)(c0 + 1) * HW + p];
        float v2 = ub[(size_t)(c0 + 2) * HW + p];
        float v3 = ub[(size_t)(c0 + 3) * HW + p];
        float v4 = ub[(size_t)(c0 + 4) * HW + p];
        float v5 = ub[(size_t)(c0 + 5) * HW + p];
        float v6 = ub[(size_t)(c0 + 6) * HW + p];
        float v7 = ub[(size_t)(c0 + 7) * HW + p];
        uint4 pk;
        pk.x = (u32)f2h(v0) | ((u32)f2h(v1) << 16);
        pk.y = (u32)f2h(v2) | ((u32)f2h(v3) << 16);
        pk.z = (u32)f2h(v4) | ((u32)f2h(v5) << 16);
        pk.w = (u32)f2h(v6) | ((u32)f2h(v7) << 16);
        *(uint4*)((char*)t_lds + p * 256 + (((c0 >> 3) ^ (p & 15)) << 4)) = pk;
      }
    }
    __syncthreads();

    // -- GEMM1: hmid(128ch) and value(128ch) for 64 px; wave owns 32 ch --
    f32x4 zero = {0.f, 0.f, 0.f, 0.f};
    f32x4 hm[2][4], va[2][4];
#pragma unroll
    for (int nt = 0; nt < 2; ++nt)
#pragma unroll
      for (int pxb = 0; pxb < 4; ++pxb) { hm[nt][pxb] = zero; va[nt][pxb] = zero; }

#pragma unroll
    for (int kc = 0; kc < 4; ++kc) {
      short8 uf[4];
#pragma unroll
      for (int pxb = 0; pxb < 4; ++pxb)
        uf[pxb] = *(const short8*)((const char*)t_lds + (pxb * 16 + m15) * 256 +
                                   ((((kc << 2) + q) ^ m15) << 4));
#pragma unroll
      for (int pxb = 0; pxb < 4; ++pxb)
#pragma unroll
        for (int nt = 0; nt < 2; ++nt) {
          hm[nt][pxb] = __builtin_amdgcn_mfma_f32_16x16x32_f16(
              w1f[nt][kc], uf[pxb], hm[nt][pxb], 0, 0, 0);
          va[nt][pxb] = __builtin_amdgcn_mfma_f32_16x16x32_f16(
              wvf[nt][kc], uf[pxb], va[nt][pxb], 0, 0, 0);
        }
    }
    __syncthreads();   // all u-tile reads done; t_lds becomes hmid

    // -- hmid: relu(h+b) -> t_lds, 4 consecutive ch per lane = one b64 write --
#pragma unroll
    for (int nt = 0; nt < 2; ++nt) {
      const int ch0   = w * 32 + nt * 16 + q * 4;
      const int chunk = ch0 >> 3;            // w*4 + nt*2 + (q>>1)
      const int inner = (ch0 & 7) << 1;      // (q&1)*8 bytes, b64-aligned
#pragma unroll
      for (int pxb = 0; pxb < 4; ++pxb) {
        const int px = pxb * 16 + m15;
        float h0 = fmaxf(hm[nt][pxb][0] + hbias[nt][0], 0.f);
        float h1 = fmaxf(hm[nt][pxb][1] + hbias[nt][1], 0.f);
        float h2 = fmaxf(hm[nt][pxb][2] + hbias[nt][2], 0.f);
        float h3 = fmaxf(hm[nt][pxb][3] + hbias[nt][3], 0.f);
        uint2 pk;
        pk.x = (u32)f2h(h0) | ((u32)f2h(h1) << 16);
        pk.y = (u32)f2h(h2) | ((u32)f2h(h3) << 16);
        *(uint2*)((char*)t_lds + px * 256 + ((chunk ^ (px & 15)) << 4) + inner) = pk;
      }
    }

    // -- value epilogue: direct interleaved store (head = ch>>2, ci = r) --
#pragma unroll
    for (int nt = 0; nt < 2; ++nt) {
      const int head = w * 8 + nt * 4 + q;
#pragma unroll
      for (int pxb = 0; pxb < 4; ++pxb) {
        f32x4 v = va[nt][pxb];
        uint2 pk;
        pk.x = (u32)f2h(v[0] + vbias[nt][0]) | ((u32)f2h(v[1] + vbias[nt][1]) << 16);
        pk.y = (u32)f2h(v[2] + vbias[nt][2]) | ((u32)f2h(v[3] + vbias[nt][3]) << 16);
        *(uint2*)(vout + ((((size_t)(b * 32 + head)) << 16) + img + pxb * 16 + m15) * 4) = pk;
      }
    }
    __syncthreads();   // hmid visible

    // -- GEMM2: flow(64 fc) for 64 px; wave owns 16 fc --
    f32x4 fl[4];
#pragma unroll
    for (int pxb = 0; pxb < 4; ++pxb) fl[pxb] = zero;
#pragma unroll
    for (int kc = 0; kc < 4; ++kc)
#pragma unroll
      for (int pxb = 0; pxb < 4; ++pxb) {
        short8 hf = *(const short8*)((const char*)t_lds + (pxb * 16 + m15) * 256 +
                                     ((((kc << 2) + q) ^ m15) << 4));
        fl[pxb] = __builtin_amdgcn_mfma_f32_16x16x32_f16(
            w2f[kc], hf, fl[pxb], 0, 0, 0);
      }

    // -- flow epilogue: lane holds (x,y) for heads h0, h0+1 of one pixel --
#pragma unroll
    for (int pxb = 0; pxb < 4; ++pxb) {
      f32x4 v = fl[pxb];
      const int h0 = w * 8 + q * 2;
      u32 pa = (u32)f2h(v[0] + fbias[0]) | ((u32)f2h(v[1] + fbias[1]) << 16);
      u32 pb = (u32)f2h(v[2] + fbias[2]) | ((u32)f2h(v[3] + fbias[3]) << 16);
      u32* fp = fout + (((size_t)(b * 32 + h0)) << 16) + img + pxb * 16 + m15;
      fp[0]  = pa;        // head h0
      fp[HW] = pb;        // head h0+1
    }
    __syncthreads();   // hmid reads done before next tile's stage
  }
}

// ---------------------------------------------------------------------------
__global__ __launch_bounds__(256) void warp_kernel(
    const u16* __restrict__ value, const u32* __restrict__ flow,
    float* __restrict__ out)
{
  // bijective XCD swizzle: 65536 blocks, 8 XCDs -> XCD x runs logical rows
  // [x*8192, (x+1)*8192) in order => row r+1 follows row r on the SAME XCD,
  // so the y/y+1 tap rows of value stay resident in that XCD's L2.
  const int P  = blockIdx.x;
  const int l  = ((P & 7) << 13) | (P >> 3);
  const int gt = (l << 8) + (int)threadIdx.x;   // (b*32+head)*HW + pix
  const int pix = gt & 65535;
  const int hb  = gt >> 16;                     // b*32 + head

  u32 f    = flow[gt];
  float fx = h2f((u16)(f & 0xffffu));
  float fy = h2f((u16)(f >> 16));

  const int wq = pix & 255, hq = pix >> 8;
  float gx = -1.f + (2.f / 255.f) * (float)wq + fx;
  float gy = -1.f + (2.f / 255.f) * (float)hq + fy;
  float pxr = ((gx + 1.f) * 256.f - 1.f) * 0.5f;
  float pyr = ((gy + 1.f) * 256.f - 1.f) * 0.5f;
  float px = pxr - floorf(pxr * (1.f / 256.f)) * 256.f;
  float py = pyr - floorf(pyr * (1.f / 256.f)) * 256.f;
  if (px >= 256.f) px -= 256.f;   // rounding guard
  if (py >= 256.f) py -= 256.f;
  if (px < 0.f) px = 0.f;
  if (py < 0.f) py = 0.f;

  float x0f = floorf(px), y0f = floorf(py);
  float wx = px - x0f, wy = py - y0f;
  int x0 = (int)x0f; if (x0 > 255) x0 = 255;
  int y0 = (int)y0f; if (y0 > 255) y0 = 255;
  int x1 = (x0 + 1) & 255;
  int y1 = (y0 + 1) & 255;

  float w00 = (1.f - wx) * (1.f - wy);
  float w01 = wx * (1.f - wy);
  float w10 = (1.f - wx) * wy;
  float w11 = wx * wy;

  // interleaved value: one tap = 4 channels = 8 B
  const u16* vb = value + ((size_t)hb << 18);
  ushort4v t00 = *(const ushort4v*)(vb + ((y0 * 256 + x0) << 2));
  ushort4v t01 = *(const ushort4v*)(vb + ((y0 * 256 + x1) << 2));
  ushort4v t10 = *(const ushort4v*)(vb + ((y1 * 256 + x0) << 2));
  ushort4v t11 = *(const ushort4v*)(vb + ((y1 * 256 + x1) << 2));

  float* ob = out + ((size_t)hb << 18) + pix;
#pragma unroll
  for (int ci = 0; ci < 4; ++ci) {
    float r = w00 * h2f(t00[ci]) + w01 * h2f(t01[ci])
            + w10 * h2f(t10[ci]) + w11 * h2f(t11[ci]);
    ob[(size_t)ci << 16] = r;
  }
}

// ---------------------------------------------------------------------------
extern "C" void kernel_launch(void* const* d_in, const int* in_sizes, int n_in,
                              void* d_out, int out_size, void* d_ws, size_t ws_size,
                              hipStream_t stream) {
  const float* u  = (const float*)d_in[0];
  const float* w1 = (const float*)d_in[1];
  const float* b1 = (const float*)d_in[2];
  const float* w2 = (const float*)d_in[3];
  const float* b2 = (const float*)d_in[4];
  const float* wv = (const float*)d_in[5];
  const float* bv = (const float*)d_in[6];

  u16* value_ws = (u16*)d_ws;                        // 134,217,728 B
  u32* flow_ws  = (u32*)((char*)d_ws + 134217728);   //  67,108,864 B
  float* out    = (float*)d_out;

  // 512 blocks = 2 resident blocks/CU (16 KB LDS, ~200 VGPR), 16 tiles each
  vf_kernel<<<dim3(512), dim3(256), 0, stream>>>(u, w1, b1, w2, b2, wv, bv,
                                                 value_ws, flow_ws);
  warp_kernel<<<dim3(65536), dim3(256), 0, stream>>>(value_ws, flow_ws, out);
}